// Round 1
// baseline (131.624 us; speedup 1.0000x reference)
//
#include <hip/hip_runtime.h>

#define LOG2E 1.4426950408889634f

typedef short bf16x8 __attribute__((ext_vector_type(8)));
typedef short short4v __attribute__((ext_vector_type(4)));
typedef float f32x4 __attribute__((ext_vector_type(4)));
typedef _Float16 half4v __attribute__((ext_vector_type(4)));
typedef unsigned __attribute__((address_space(1))) u32g;
typedef unsigned __attribute__((address_space(3))) u32l;

#define MFMA16(a, b, c) __builtin_amdgcn_mfma_f32_16x16x32_bf16((a), (b), (c), 0, 0, 0)

__device__ __forceinline__ short f2bf(float f) {
  unsigned u = __builtin_bit_cast(unsigned, f);
  u += 0x7FFFu + ((u >> 16) & 1u);
  return (short)(u >> 16);
}

__device__ __forceinline__ void g2l16(void* lds, const void* g) {
  __builtin_amdgcn_global_load_lds((u32g*)const_cast<void*>(g), (u32l*)lds, 16, 0, 0);
}

// ---------------------------------------------------------------------------
// GroupNorm: x (B,512,1024) f32 -> xn_t (B,1024,512) bf16   [transposed for GEMM]
// block = one (b, group): 16 channels x 1024 spatial. fp16 LDS stash avoids a
// second (scattered) global read; XOR swizzle kills the transpose bank conflict.
// ---------------------------------------------------------------------------
__global__ __launch_bounds__(256) void gn_kernel(const float* __restrict__ x,
                                                 const float* __restrict__ gamma,
                                                 const float* __restrict__ beta,
                                                 short* __restrict__ xn_t) {
  __shared__ _Float16 xs[16 * 1024];  // 32 KB, row = channel, swizzled
  __shared__ float red[8];
  const int bg = blockIdx.x;
  const int b = bg >> 5, g = bg & 31;
  const int t = threadIdx.x;
  const float4* gx4 = (const float4*)(x + (size_t)(b * 512 + g * 16) * 1024);
  float s1 = 0.f, s2 = 0.f;
  for (int i = 0; i < 16; ++i) {  // i == channel-in-group, thread t covers n=4t..4t+3
    float4 v = gx4[t + 256 * i];
    s1 += (v.x + v.y) + (v.z + v.w);
    s2 += (v.x * v.x + v.y * v.y) + (v.z * v.z + v.w * v.w);
    half4v pk = {(_Float16)v.x, (_Float16)v.y, (_Float16)v.z, (_Float16)v.w};
    *(half4v*)((char*)xs + i * 2048 + ((8 * t) ^ ((i & 7) << 4))) = pk;
  }
  for (int m = 1; m < 64; m <<= 1) {
    s1 += __shfl_xor(s1, m);
    s2 += __shfl_xor(s2, m);
  }
  if ((t & 63) == 0) {
    red[(t >> 6) * 2] = s1;
    red[(t >> 6) * 2 + 1] = s2;
  }
  __syncthreads();
  s1 = (red[0] + red[2]) + (red[4] + red[6]);
  s2 = (red[1] + red[3]) + (red[5] + red[7]);
  const float mean = s1 * (1.f / 16384.f);
  const float var = s2 * (1.f / 16384.f) - mean * mean;
  const float rstd = rsqrtf(var + 1e-6f);
  const int ci = t & 15;
  const float ga = gamma[g * 16 + ci] * rstd;
  const float be = beta[g * 16 + ci] - mean * ga;
  short* dst = xn_t + (size_t)b * 1024 * 512 + g * 16 + ci;
  const int sw = (ci & 7) << 4;
  for (int i = 0; i < 64; ++i) {
    int n = (t >> 4) + 16 * i;
    float v = (float)*(const _Float16*)((const char*)xs + ci * 2048 + ((2 * n) ^ sw));
    dst[(size_t)n * 512] = f2bf(fmaf(v, ga, be));
  }
}

// ---------------------------------------------------------------------------
// f32 -> bf16 weight conversion (vec4)
// ---------------------------------------------------------------------------
__global__ __launch_bounds__(256) void f2bf_kernel(const float* __restrict__ src,
                                                   short* __restrict__ dst, int n4) {
  int i = blockIdx.x * 256 + threadIdx.x;
  if (i < n4) {
    float4 v = ((const float4*)src)[i];
    short4v o = {f2bf(v.x), f2bf(v.y), f2bf(v.z), f2bf(v.w)};
    *(short4v*)(dst + (size_t)i * 4) = o;
  }
}

// ---------------------------------------------------------------------------
// QKV GEMM: W(1536x512 bf16, row-major) x xn_t[b] ([n][c] bf16) -> q,k,v^T
// 128x128 tile, BK=32, global_load_lds(16B) staging, 4 waves, 4x4 frags/wave.
// q,k stored (bh, n, d) row-major; v stored transposed (bh, d, n).
// ---------------------------------------------------------------------------
__global__ __launch_bounds__(256) void qkv_gemm(const short* __restrict__ W,
                                                const short* __restrict__ xn,
                                                const float* __restrict__ bias,
                                                short* __restrict__ qbuf,
                                                short* __restrict__ kbuf,
                                                short* __restrict__ vtbuf) {
  __shared__ short a_sm[128 * 32];
  __shared__ short b_sm[128 * 32];
  const int t = threadIdx.x;
  const int lane = t & 63, w = t >> 6;
  const int nbase = blockIdx.x * 128;
  const int mbase = blockIdx.y * 128;
  const int b = blockIdx.z;
  const short* Asrc = W + (size_t)mbase * 512;
  const short* Bsrc = xn + (size_t)b * 1024 * 512 + (size_t)nbase * 512;

  const int j0 = (w * 2) * 64 + lane;  // 16B chunk ids for staging
  const int j1 = j0 + 64;
  const int r0 = j0 >> 2, c0 = (j0 & 3) * 8;
  const int r1 = j1 >> 2, c1 = (j1 & 3) * 8;

  const int wm = (w >> 1) * 64, wn = (w & 1) * 64;
  const int col = lane & 15, rg = lane >> 4, koff = rg * 8;

  f32x4 acc[4][4] = {};

  for (int kt = 0; kt < 16; ++kt) {
    const int k0 = kt * 32;
    g2l16(&a_sm[(w * 2) * 512], Asrc + (size_t)r0 * 512 + k0 + c0);
    g2l16(&a_sm[(w * 2 + 1) * 512], Asrc + (size_t)r1 * 512 + k0 + c1);
    g2l16(&b_sm[(w * 2) * 512], Bsrc + (size_t)r0 * 512 + k0 + c0);
    g2l16(&b_sm[(w * 2 + 1) * 512], Bsrc + (size_t)r1 * 512 + k0 + c1);
    __syncthreads();
    bf16x8 af[4], bfr[4];
    for (int mf = 0; mf < 4; ++mf)
      af[mf] = *(const bf16x8*)&a_sm[(wm + mf * 16 + col) * 32 + koff];
    for (int nf = 0; nf < 4; ++nf)
      bfr[nf] = *(const bf16x8*)&b_sm[(wn + nf * 16 + col) * 32 + koff];
    for (int mf = 0; mf < 4; ++mf)
      for (int nf = 0; nf < 4; ++nf)
        acc[mf][nf] = MFMA16(af[mf], bfr[nf], acc[mf][nf]);
    __syncthreads();
  }

  const int section = mbase >> 9;  // 0=q, 1=k, 2=v (128-tiles never straddle)
  for (int mf = 0; mf < 4; ++mf) {
    const int o0 = mbase + wm + mf * 16 + rg * 4;
    const int h = (o0 >> 6) & 7, d0 = o0 & 63;
    float b4[4];
    for (int r = 0; r < 4; ++r) b4[r] = bias[o0 + r];
    for (int nf = 0; nf < 4; ++nf) {
      const int n = nbase + wn + nf * 16 + col;
      if (section < 2) {
        short4v pk;
        for (int r = 0; r < 4; ++r) pk[r] = f2bf(acc[mf][nf][r] + b4[r]);
        short* dst = (section == 0) ? qbuf : kbuf;
        *(short4v*)&dst[((size_t)(b * 8 + h) * 1024 + n) * 64 + d0] = pk;
      } else {
        for (int r = 0; r < 4; ++r)
          vtbuf[((size_t)(b * 8 + h) * 64 + d0 + r) * 1024 + n] =
              f2bf(acc[mf][nf][r] + b4[r]);
      }
    }
  }
}

// ---------------------------------------------------------------------------
// Flash attention: block = (qtile of 128, h, b), 4 waves x 32 q-rows.
// K tile [128][64] and V^T tile [64][128] in XOR-swizzled LDS; P transits a
// per-wave swizzled LDS tile (D-layout -> A-fragment transpose).
// Output written (b, n, h*64+d) bf16 = [n][c] for the proj GEMM.
// ---------------------------------------------------------------------------
__global__ __launch_bounds__(256) void attn_kernel(const short* __restrict__ qbuf,
                                                   const short* __restrict__ kbuf,
                                                   const short* __restrict__ vtbuf,
                                                   short* __restrict__ ao) {
  __shared__ short k_sm[128 * 64];       // 16 KB
  __shared__ short v_sm[64 * 128];       // 16 KB
  __shared__ short p_sm[4 * 32 * 128];   // 32 KB (8 KB per wave)
  const int t = threadIdx.x, lane = t & 63, w = t >> 6;
  const int col = lane & 15, rg = lane >> 4;
  const int qt = blockIdx.x, h = blockIdx.y, b = blockIdx.z;
  const int bh = b * 8 + h;
  const int qbase = qt * 128;

  bf16x8 aq[2][2];
  {
    const short* qp = qbuf + ((size_t)bh * 1024 + qbase + w * 32) * 64;
    for (int mf = 0; mf < 2; ++mf)
      for (int kc = 0; kc < 2; ++kc)
        aq[mf][kc] = *(const bf16x8*)&qp[(mf * 16 + col) * 64 + kc * 32 + rg * 8];
  }

  f32x4 oacc[2][4] = {};
  float mrun[2][4], lrun[2][4];
  for (int mf = 0; mf < 2; ++mf)
    for (int r = 0; r < 4; ++r) {
      mrun[mf][r] = -1e30f;
      lrun[mf][r] = 0.f;
    }

  const float kSL2E = 0.125f * LOG2E;  // scale * log2(e)
  const short* kp0 = kbuf + (size_t)bh * 1024 * 64;
  const short* vp0 = vtbuf + (size_t)bh * 64 * 1024;

  for (int kt = 0; kt < 8; ++kt) {
    __syncthreads();
    for (int c = 0; c < 4; ++c) {  // stage K: rows n, 128B each, swizzled
      int j = c * 256 + t;
      int row = j >> 3, off = j & 7;
      uint4 dk = *(const uint4*)&kp0[((size_t)kt * 128 + row) * 64 + off * 8];
      *(uint4*)((char*)k_sm + row * 128 + ((off * 16) ^ ((row & 7) << 4))) = dk;
    }
    for (int c = 0; c < 4; ++c) {  // stage V^T: rows d, 256B each, swizzled
      int j = c * 256 + t;
      int row = j >> 4, off = j & 15;
      uint4 dv = *(const uint4*)&vp0[(size_t)row * 1024 + kt * 128 + off * 8];
      *(uint4*)((char*)v_sm + row * 256 + ((off * 16) ^ ((row & 7) << 4))) = dv;
    }
    __syncthreads();

    // S = Q K^T  (rows = q, cols = kj)
    f32x4 s[2][8];
    for (int nf = 0; nf < 8; ++nf) {
      const int n = nf * 16 + col;
      const char* kb = (const char*)k_sm + n * 128;
      const int sw = (n & 7) << 4;
      bf16x8 bk0 = *(const bf16x8*)(kb + ((rg * 16) ^ sw));
      bf16x8 bk1 = *(const bf16x8*)(kb + ((64 + rg * 16) ^ sw));
      for (int mf = 0; mf < 2; ++mf) {
        f32x4 z = {};
        z = MFMA16(aq[mf][0], bk0, z);
        s[mf][nf] = MFMA16(aq[mf][1], bk1, z);
      }
    }

    // online softmax (row stats; cols spread over the 16 low lanes + 8 frags)
    for (int mf = 0; mf < 2; ++mf) {
      char* pbase = (char*)p_sm + (w * 32 + mf * 16) * 256;
      for (int r = 0; r < 4; ++r) {
        float mx = s[mf][0][r];
        for (int nf = 1; nf < 8; ++nf) mx = fmaxf(mx, s[mf][nf][r]);
        mx = fmaxf(mx, __shfl_xor(mx, 1));
        mx = fmaxf(mx, __shfl_xor(mx, 2));
        mx = fmaxf(mx, __shfl_xor(mx, 4));
        mx = fmaxf(mx, __shfl_xor(mx, 8));
        const float mnew = fmaxf(mrun[mf][r], mx * 0.125f);
        const float alpha = exp2f((mrun[mf][r] - mnew) * LOG2E);
        mrun[mf][r] = mnew;
        const float nege = mnew * LOG2E;
        char* prp = pbase + (rg * 4 + r) * 256;
        const int swp = ((rg * 4 + r) & 7) << 4;
        float psum = 0.f;
        for (int nf = 0; nf < 8; ++nf) {
          float p = exp2f(fmaf(s[mf][nf][r], kSL2E, -nege));
          psum += p;
          *(short*)(prp + (((nf * 16 + col) * 2) ^ swp)) = f2bf(p);
        }
        psum += __shfl_xor(psum, 1);
        psum += __shfl_xor(psum, 2);
        psum += __shfl_xor(psum, 4);
        psum += __shfl_xor(psum, 8);
        lrun[mf][r] = lrun[mf][r] * alpha + psum;
        for (int df = 0; df < 4; ++df) oacc[mf][df][r] *= alpha;
      }
    }

    // O += P V   (p_sm is wave-private: in-order LDS, no barrier needed)
    for (int kc = 0; kc < 4; ++kc) {
      bf16x8 pa[2];
      for (int mf = 0; mf < 2; ++mf) {
        const int prow = w * 32 + mf * 16 + col;
        pa[mf] = *(const bf16x8*)((const char*)p_sm + prow * 256 +
                                  ((kc * 64 + rg * 16) ^ ((prow & 7) << 4)));
      }
      for (int df = 0; df < 4; ++df) {
        const int d = df * 16 + col;
        bf16x8 bv = *(const bf16x8*)((const char*)v_sm + d * 256 +
                                     ((kc * 64 + rg * 16) ^ ((d & 7) << 4)));
        for (int mf = 0; mf < 2; ++mf)
          oacc[mf][df] = MFMA16(pa[mf], bv, oacc[mf][df]);
      }
    }
  }

  for (int mf = 0; mf < 2; ++mf) {
    for (int r = 0; r < 4; ++r) {
      const float rl = 1.f / lrun[mf][r];
      const int q = qbase + w * 32 + mf * 16 + rg * 4 + r;
      short* dst = ao + ((size_t)b * 1024 + q) * 512 + h * 64;
      for (int df = 0; df < 4; ++df) dst[df * 16 + col] = f2bf(oacc[mf][df][r] * rl);
    }
  }
}

// ---------------------------------------------------------------------------
// Proj GEMM + bias + fp32 residual: out = x + W_proj @ ao
// ---------------------------------------------------------------------------
__global__ __launch_bounds__(256) void proj_gemm(const short* __restrict__ W,
                                                 const short* __restrict__ ao,
                                                 const float* __restrict__ bias,
                                                 const float* __restrict__ x,
                                                 float* __restrict__ out) {
  __shared__ short a_sm[128 * 32];
  __shared__ short b_sm[128 * 32];
  const int t = threadIdx.x;
  const int lane = t & 63, w = t >> 6;
  const int nbase = blockIdx.x * 128;
  const int mbase = blockIdx.y * 128;
  const int b = blockIdx.z;
  const short* Asrc = W + (size_t)mbase * 512;
  const short* Bsrc = ao + (size_t)b * 1024 * 512 + (size_t)nbase * 512;

  const int j0 = (w * 2) * 64 + lane;
  const int j1 = j0 + 64;
  const int r0 = j0 >> 2, c0 = (j0 & 3) * 8;
  const int r1 = j1 >> 2, c1 = (j1 & 3) * 8;

  const int wm = (w >> 1) * 64, wn = (w & 1) * 64;
  const int col = lane & 15, rg = lane >> 4, koff = rg * 8;

  f32x4 acc[4][4] = {};

  for (int kt = 0; kt < 16; ++kt) {
    const int k0 = kt * 32;
    g2l16(&a_sm[(w * 2) * 512], Asrc + (size_t)r0 * 512 + k0 + c0);
    g2l16(&a_sm[(w * 2 + 1) * 512], Asrc + (size_t)r1 * 512 + k0 + c1);
    g2l16(&b_sm[(w * 2) * 512], Bsrc + (size_t)r0 * 512 + k0 + c0);
    g2l16(&b_sm[(w * 2 + 1) * 512], Bsrc + (size_t)r1 * 512 + k0 + c1);
    __syncthreads();
    bf16x8 af[4], bfr[4];
    for (int mf = 0; mf < 4; ++mf)
      af[mf] = *(const bf16x8*)&a_sm[(wm + mf * 16 + col) * 32 + koff];
    for (int nf = 0; nf < 4; ++nf)
      bfr[nf] = *(const bf16x8*)&b_sm[(wn + nf * 16 + col) * 32 + koff];
    for (int mf = 0; mf < 4; ++mf)
      for (int nf = 0; nf < 4; ++nf)
        acc[mf][nf] = MFMA16(af[mf], bfr[nf], acc[mf][nf]);
    __syncthreads();
  }

  for (int mf = 0; mf < 4; ++mf) {
    const int o0 = mbase + wm + mf * 16 + rg * 4;
    float b4[4];
    for (int r = 0; r < 4; ++r) b4[r] = bias[o0 + r];
    for (int nf = 0; nf < 4; ++nf) {
      const int n = nbase + wn + nf * 16 + col;
      for (int r = 0; r < 4; ++r) {
        size_t idx = ((size_t)b * 512 + o0 + r) * 1024 + n;
        out[idx] = x[idx] + acc[mf][nf][r] + b4[r];
      }
    }
  }
}

// ---------------------------------------------------------------------------
extern "C" void kernel_launch(void* const* d_in, const int* in_sizes, int n_in,
                              void* d_out, int out_size, void* d_ws, size_t ws_size,
                              hipStream_t stream) {
  const float* x = (const float*)d_in[0];
  const float* gamma = (const float*)d_in[1];
  const float* beta = (const float*)d_in[2];
  const float* w_qkv = (const float*)d_in[3];
  const float* b_qkv = (const float*)d_in[4];
  const float* w_proj = (const float*)d_in[5];
  const float* b_proj = (const float*)d_in[6];
  float* out = (float*)d_out;

  char* ws = (char*)d_ws;
  short* xn_t = (short*)(ws);                  // 8 MB   (B,N,C) bf16
  short* wqkv_b = (short*)(ws + 8388608);      // 1.5 MB
  short* wproj_b = (short*)(ws + 9961472);     // 0.5 MB
  short* qbuf = (short*)(ws + 10485760);       // 8 MB   (BH,N,d)
  short* kbuf = (short*)(ws + 18874368);       // 8 MB   (BH,N,d)
  short* vtbuf = (short*)(ws + 27262976);      // 8 MB   (BH,d,N)
  short* aobuf = (short*)(ws + 35651584);      // 8 MB   (B,N,C)

  gn_kernel<<<dim3(256), dim3(256), 0, stream>>>(x, gamma, beta, xn_t);
  f2bf_kernel<<<dim3(768), dim3(256), 0, stream>>>(w_qkv, wqkv_b, 196608);
  f2bf_kernel<<<dim3(256), dim3(256), 0, stream>>>(w_proj, wproj_b, 65536);
  qkv_gemm<<<dim3(8, 12, 8), dim3(256), 0, stream>>>(wqkv_b, xn_t, b_qkv, qbuf, kbuf,
                                                     vtbuf);
  attn_kernel<<<dim3(8, 8, 8), dim3(256), 0, stream>>>(qbuf, kbuf, vtbuf, aobuf);
  proj_gemm<<<dim3(8, 4, 8), dim3(256), 0, stream>>>(wproj_b, aobuf, b_proj, x, out);
}

// Round 2
// 129.366 us; speedup vs baseline: 1.0174x; 1.0174x over previous
//
#include <hip/hip_runtime.h>

#define LOG2E 1.4426950408889634f

typedef short bf16x8 __attribute__((ext_vector_type(8)));
typedef short short4v __attribute__((ext_vector_type(4)));
typedef float f32x4 __attribute__((ext_vector_type(4)));
typedef _Float16 half4v __attribute__((ext_vector_type(4)));
typedef unsigned __attribute__((address_space(1))) u32g;
typedef unsigned __attribute__((address_space(3))) u32l;

#define MFMA16(a, b, c) __builtin_amdgcn_mfma_f32_16x16x32_bf16((a), (b), (c), 0, 0, 0)

__device__ __forceinline__ short f2bf(float f) {
  unsigned u = __builtin_bit_cast(unsigned, f);
  u += 0x7FFFu + ((u >> 16) & 1u);
  return (short)(u >> 16);
}

__device__ __forceinline__ void g2l16(void* lds, const void* g) {
  __builtin_amdgcn_global_load_lds((u32g*)const_cast<void*>(g), (u32l*)lds, 16, 0, 0);
}

// ---------------------------------------------------------------------------
// GroupNorm: x (B,512,1024) f32 -> xn_t (B,1024,512) bf16   [transposed for GEMM]
// block = one (b, group): 16 channels x 1024 spatial. fp16 LDS stash avoids a
// second (scattered) global read; XOR swizzle kills the transpose bank conflict.
// ---------------------------------------------------------------------------
__global__ __launch_bounds__(256) void gn_kernel(const float* __restrict__ x,
                                                 const float* __restrict__ gamma,
                                                 const float* __restrict__ beta,
                                                 short* __restrict__ xn_t) {
  __shared__ _Float16 xs[16 * 1024];  // 32 KB, row = channel, swizzled
  __shared__ float red[8];
  const int bg = blockIdx.x;
  const int b = bg >> 5, g = bg & 31;
  const int t = threadIdx.x;
  const float4* gx4 = (const float4*)(x + (size_t)(b * 512 + g * 16) * 1024);
  float s1 = 0.f, s2 = 0.f;
  for (int i = 0; i < 16; ++i) {  // i == channel-in-group, thread t covers n=4t..4t+3
    float4 v = gx4[t + 256 * i];
    s1 += (v.x + v.y) + (v.z + v.w);
    s2 += (v.x * v.x + v.y * v.y) + (v.z * v.z + v.w * v.w);
    half4v pk = {(_Float16)v.x, (_Float16)v.y, (_Float16)v.z, (_Float16)v.w};
    *(half4v*)((char*)xs + i * 2048 + ((8 * t) ^ ((i & 7) << 4))) = pk;
  }
  for (int m = 1; m < 64; m <<= 1) {
    s1 += __shfl_xor(s1, m);
    s2 += __shfl_xor(s2, m);
  }
  if ((t & 63) == 0) {
    red[(t >> 6) * 2] = s1;
    red[(t >> 6) * 2 + 1] = s2;
  }
  __syncthreads();
  s1 = (red[0] + red[2]) + (red[4] + red[6]);
  s2 = (red[1] + red[3]) + (red[5] + red[7]);
  const float mean = s1 * (1.f / 16384.f);
  const float var = s2 * (1.f / 16384.f) - mean * mean;
  const float rstd = rsqrtf(var + 1e-6f);
  const int ci = t & 15;
  const float ga = gamma[g * 16 + ci] * rstd;
  const float be = beta[g * 16 + ci] - mean * ga;
  short* dst = xn_t + (size_t)b * 1024 * 512 + g * 16 + ci;
  const int sw = (ci & 7) << 4;
  for (int i = 0; i < 64; ++i) {
    int n = (t >> 4) + 16 * i;
    float v = (float)*(const _Float16*)((const char*)xs + ci * 2048 + ((2 * n) ^ sw));
    dst[(size_t)n * 512] = f2bf(fmaf(v, ga, be));
  }
}

// ---------------------------------------------------------------------------
// f32 -> bf16 weight conversion (vec4)
// ---------------------------------------------------------------------------
__global__ __launch_bounds__(256) void f2bf_kernel(const float* __restrict__ src,
                                                   short* __restrict__ dst, int n4) {
  int i = blockIdx.x * 256 + threadIdx.x;
  if (i < n4) {
    float4 v = ((const float4*)src)[i];
    short4v o = {f2bf(v.x), f2bf(v.y), f2bf(v.z), f2bf(v.w)};
    *(short4v*)(dst + (size_t)i * 4) = o;
  }
}

// ---------------------------------------------------------------------------
// QKV GEMM: W(1536x512 bf16, row-major) x xn_t[b] ([n][c] bf16) -> q,k,v^T
// 128x128 tile, BK=32, global_load_lds(16B) staging, 4 waves, 4x4 frags/wave.
// q,k stored (bh, n, d) row-major; v stored transposed (bh, d, n).
// ---------------------------------------------------------------------------
__global__ __launch_bounds__(256) void qkv_gemm(const short* __restrict__ W,
                                                const short* __restrict__ xn,
                                                const float* __restrict__ bias,
                                                short* __restrict__ qbuf,
                                                short* __restrict__ kbuf,
                                                short* __restrict__ vtbuf) {
  __shared__ short a_sm[128 * 32];
  __shared__ short b_sm[128 * 32];
  const int t = threadIdx.x;
  const int lane = t & 63, w = t >> 6;
  const int nbase = blockIdx.x * 128;
  const int mbase = blockIdx.y * 128;
  const int b = blockIdx.z;
  const short* Asrc = W + (size_t)mbase * 512;
  const short* Bsrc = xn + (size_t)b * 1024 * 512 + (size_t)nbase * 512;

  const int j0 = (w * 2) * 64 + lane;  // 16B chunk ids for staging
  const int j1 = j0 + 64;
  const int r0 = j0 >> 2, c0 = (j0 & 3) * 8;
  const int r1 = j1 >> 2, c1 = (j1 & 3) * 8;

  const int wm = (w >> 1) * 64, wn = (w & 1) * 64;
  const int col = lane & 15, rg = lane >> 4, koff = rg * 8;

  f32x4 acc[4][4] = {};

  for (int kt = 0; kt < 16; ++kt) {
    const int k0 = kt * 32;
    g2l16(&a_sm[(w * 2) * 512], Asrc + (size_t)r0 * 512 + k0 + c0);
    g2l16(&a_sm[(w * 2 + 1) * 512], Asrc + (size_t)r1 * 512 + k0 + c1);
    g2l16(&b_sm[(w * 2) * 512], Bsrc + (size_t)r0 * 512 + k0 + c0);
    g2l16(&b_sm[(w * 2 + 1) * 512], Bsrc + (size_t)r1 * 512 + k0 + c1);
    __syncthreads();
    bf16x8 af[4], bfr[4];
    for (int mf = 0; mf < 4; ++mf)
      af[mf] = *(const bf16x8*)&a_sm[(wm + mf * 16 + col) * 32 + koff];
    for (int nf = 0; nf < 4; ++nf)
      bfr[nf] = *(const bf16x8*)&b_sm[(wn + nf * 16 + col) * 32 + koff];
    for (int mf = 0; mf < 4; ++mf)
      for (int nf = 0; nf < 4; ++nf)
        acc[mf][nf] = MFMA16(af[mf], bfr[nf], acc[mf][nf]);
    __syncthreads();
  }

  const int section = mbase >> 9;  // 0=q, 1=k, 2=v (128-tiles never straddle)
  for (int mf = 0; mf < 4; ++mf) {
    const int o0 = mbase + wm + mf * 16 + rg * 4;
    const int h = (o0 >> 6) & 7, d0 = o0 & 63;
    float b4[4];
    for (int r = 0; r < 4; ++r) b4[r] = bias[o0 + r];
    for (int nf = 0; nf < 4; ++nf) {
      const int n = nbase + wn + nf * 16 + col;
      if (section < 2) {
        short4v pk;
        for (int r = 0; r < 4; ++r) pk[r] = f2bf(acc[mf][nf][r] + b4[r]);
        short* dst = (section == 0) ? qbuf : kbuf;
        *(short4v*)&dst[((size_t)(b * 8 + h) * 1024 + n) * 64 + d0] = pk;
      } else {
        for (int r = 0; r < 4; ++r)
          vtbuf[((size_t)(b * 8 + h) * 64 + d0 + r) * 1024 + n] =
              f2bf(acc[mf][nf][r] + b4[r]);
      }
    }
  }
}

// ---------------------------------------------------------------------------
// Flash attention: block = (qtile of 128, h, b), 4 waves x 32 q-rows.
// K tile [128][64] and V^T tile [64][128] in XOR-swizzled LDS; P transits a
// per-wave swizzled LDS tile (D-layout -> A-fragment transpose).
// Output written (b, n, h*64+d) bf16 = [n][c] for the proj GEMM.
// ---------------------------------------------------------------------------
__global__ __launch_bounds__(256) void attn_kernel(const short* __restrict__ qbuf,
                                                   const short* __restrict__ kbuf,
                                                   const short* __restrict__ vtbuf,
                                                   short* __restrict__ ao) {
  __shared__ short k_sm[128 * 64];       // 16 KB
  __shared__ short v_sm[64 * 128];       // 16 KB
  __shared__ short p_sm[4 * 32 * 128];   // 32 KB (8 KB per wave)
  const int t = threadIdx.x, lane = t & 63, w = t >> 6;
  const int col = lane & 15, rg = lane >> 4;
  const int qt = blockIdx.x, h = blockIdx.y, b = blockIdx.z;
  const int bh = b * 8 + h;
  const int qbase = qt * 128;

  bf16x8 aq[2][2];
  {
    const short* qp = qbuf + ((size_t)bh * 1024 + qbase + w * 32) * 64;
    for (int mf = 0; mf < 2; ++mf)
      for (int kc = 0; kc < 2; ++kc)
        aq[mf][kc] = *(const bf16x8*)&qp[(mf * 16 + col) * 64 + kc * 32 + rg * 8];
  }

  f32x4 oacc[2][4] = {};
  float mrun[2][4], lrun[2][4];
  for (int mf = 0; mf < 2; ++mf)
    for (int r = 0; r < 4; ++r) {
      mrun[mf][r] = -1e30f;
      lrun[mf][r] = 0.f;
    }

  const float kSL2E = 0.125f * LOG2E;  // scale * log2(e)
  const short* kp0 = kbuf + (size_t)bh * 1024 * 64;
  const short* vp0 = vtbuf + (size_t)bh * 64 * 1024;

  for (int kt = 0; kt < 8; ++kt) {
    __syncthreads();
    for (int c = 0; c < 4; ++c) {  // stage K: rows n, 128B each, swizzled
      int j = c * 256 + t;
      int row = j >> 3, off = j & 7;
      uint4 dk = *(const uint4*)&kp0[((size_t)kt * 128 + row) * 64 + off * 8];
      *(uint4*)((char*)k_sm + row * 128 + ((off * 16) ^ ((row & 7) << 4))) = dk;
    }
    for (int c = 0; c < 4; ++c) {  // stage V^T: rows d, 256B each, swizzled
      int j = c * 256 + t;
      int row = j >> 4, off = j & 15;
      uint4 dv = *(const uint4*)&vp0[(size_t)row * 1024 + kt * 128 + off * 8];
      *(uint4*)((char*)v_sm + row * 256 + ((off * 16) ^ ((row & 7) << 4))) = dv;
    }
    __syncthreads();

    // S = Q K^T  (rows = q, cols = kj)
    f32x4 s[2][8];
    for (int nf = 0; nf < 8; ++nf) {
      const int n = nf * 16 + col;
      const char* kb = (const char*)k_sm + n * 128;
      const int sw = (n & 7) << 4;
      bf16x8 bk0 = *(const bf16x8*)(kb + ((rg * 16) ^ sw));
      bf16x8 bk1 = *(const bf16x8*)(kb + ((64 + rg * 16) ^ sw));
      for (int mf = 0; mf < 2; ++mf) {
        f32x4 z = {};
        z = MFMA16(aq[mf][0], bk0, z);
        s[mf][nf] = MFMA16(aq[mf][1], bk1, z);
      }
    }

    // online softmax (row stats; cols spread over the 16 low lanes + 8 frags)
    for (int mf = 0; mf < 2; ++mf) {
      char* pbase = (char*)p_sm + (w * 32 + mf * 16) * 256;
      for (int r = 0; r < 4; ++r) {
        float mx = s[mf][0][r];
        for (int nf = 1; nf < 8; ++nf) mx = fmaxf(mx, s[mf][nf][r]);
        mx = fmaxf(mx, __shfl_xor(mx, 1));
        mx = fmaxf(mx, __shfl_xor(mx, 2));
        mx = fmaxf(mx, __shfl_xor(mx, 4));
        mx = fmaxf(mx, __shfl_xor(mx, 8));
        const float mnew = fmaxf(mrun[mf][r], mx * 0.125f);
        const float alpha = exp2f((mrun[mf][r] - mnew) * LOG2E);
        mrun[mf][r] = mnew;
        const float nege = mnew * LOG2E;
        char* prp = pbase + (rg * 4 + r) * 256;
        const int swp = ((rg * 4 + r) & 7) << 4;
        float psum = 0.f;
        for (int nf = 0; nf < 8; ++nf) {
          float p = exp2f(fmaf(s[mf][nf][r], kSL2E, -nege));
          psum += p;
          *(short*)(prp + (((nf * 16 + col) * 2) ^ swp)) = f2bf(p);
        }
        psum += __shfl_xor(psum, 1);
        psum += __shfl_xor(psum, 2);
        psum += __shfl_xor(psum, 4);
        psum += __shfl_xor(psum, 8);
        lrun[mf][r] = lrun[mf][r] * alpha + psum;
        for (int df = 0; df < 4; ++df) oacc[mf][df][r] *= alpha;
      }
    }

    // O += P V   (p_sm is wave-private: in-order LDS, no barrier needed)
    for (int kc = 0; kc < 4; ++kc) {
      bf16x8 pa[2];
      for (int mf = 0; mf < 2; ++mf) {
        const int prow = w * 32 + mf * 16 + col;
        pa[mf] = *(const bf16x8*)((const char*)p_sm + prow * 256 +
                                  ((kc * 64 + rg * 16) ^ ((prow & 7) << 4)));
      }
      for (int df = 0; df < 4; ++df) {
        const int d = df * 16 + col;
        bf16x8 bv = *(const bf16x8*)((const char*)v_sm + d * 256 +
                                     ((kc * 64 + rg * 16) ^ ((d & 7) << 4)));
        for (int mf = 0; mf < 2; ++mf)
          oacc[mf][df] = MFMA16(pa[mf], bv, oacc[mf][df]);
      }
    }
  }

  for (int mf = 0; mf < 2; ++mf) {
    for (int r = 0; r < 4; ++r) {
      const float rl = 1.f / lrun[mf][r];
      const int q = qbase + w * 32 + mf * 16 + rg * 4 + r;
      short* dst = ao + ((size_t)b * 1024 + q) * 512 + h * 64;
      for (int df = 0; df < 4; ++df) dst[df * 16 + col] = f2bf(oacc[mf][df][r] * rl);
    }
  }
}

// ---------------------------------------------------------------------------
// Proj GEMM + bias + fp32 residual: out = x + W_proj @ ao
// ---------------------------------------------------------------------------
__global__ __launch_bounds__(256) void proj_gemm(const short* __restrict__ W,
                                                 const short* __restrict__ ao,
                                                 const float* __restrict__ bias,
                                                 const float* __restrict__ x,
                                                 float* __restrict__ out) {
  __shared__ short a_sm[128 * 32];
  __shared__ short b_sm[128 * 32];
  const int t = threadIdx.x;
  const int lane = t & 63, w = t >> 6;
  const int nbase = blockIdx.x * 128;
  const int mbase = blockIdx.y * 128;
  const int b = blockIdx.z;
  const short* Asrc = W + (size_t)mbase * 512;
  const short* Bsrc = ao + (size_t)b * 1024 * 512 + (size_t)nbase * 512;

  const int j0 = (w * 2) * 64 + lane;
  const int j1 = j0 + 64;
  const int r0 = j0 >> 2, c0 = (j0 & 3) * 8;
  const int r1 = j1 >> 2, c1 = (j1 & 3) * 8;

  const int wm = (w >> 1) * 64, wn = (w & 1) * 64;
  const int col = lane & 15, rg = lane >> 4, koff = rg * 8;

  f32x4 acc[4][4] = {};

  for (int kt = 0; kt < 16; ++kt) {
    const int k0 = kt * 32;
    g2l16(&a_sm[(w * 2) * 512], Asrc + (size_t)r0 * 512 + k0 + c0);
    g2l16(&a_sm[(w * 2 + 1) * 512], Asrc + (size_t)r1 * 512 + k0 + c1);
    g2l16(&b_sm[(w * 2) * 512], Bsrc + (size_t)r0 * 512 + k0 + c0);
    g2l16(&b_sm[(w * 2 + 1) * 512], Bsrc + (size_t)r1 * 512 + k0 + c1);
    __syncthreads();
    bf16x8 af[4], bfr[4];
    for (int mf = 0; mf < 4; ++mf)
      af[mf] = *(const bf16x8*)&a_sm[(wm + mf * 16 + col) * 32 + koff];
    for (int nf = 0; nf < 4; ++nf)
      bfr[nf] = *(const bf16x8*)&b_sm[(wn + nf * 16 + col) * 32 + koff];
    for (int mf = 0; mf < 4; ++mf)
      for (int nf = 0; nf < 4; ++nf)
        acc[mf][nf] = MFMA16(af[mf], bfr[nf], acc[mf][nf]);
    __syncthreads();
  }

  for (int mf = 0; mf < 4; ++mf) {
    const int o0 = mbase + wm + mf * 16 + rg * 4;
    float b4[4];
    for (int r = 0; r < 4; ++r) b4[r] = bias[o0 + r];
    for (int nf = 0; nf < 4; ++nf) {
      const int n = nbase + wn + nf * 16 + col;
      for (int r = 0; r < 4; ++r) {
        size_t idx = ((size_t)b * 512 + o0 + r) * 1024 + n;
        out[idx] = x[idx] + acc[mf][nf][r] + b4[r];
      }
    }
  }
}

// ---------------------------------------------------------------------------
extern "C" void kernel_launch(void* const* d_in, const int* in_sizes, int n_in,
                              void* d_out, int out_size, void* d_ws, size_t ws_size,
                              hipStream_t stream) {
  const float* x = (const float*)d_in[0];
  const float* gamma = (const float*)d_in[1];
  const float* beta = (const float*)d_in[2];
  const float* w_qkv = (const float*)d_in[3];
  const float* b_qkv = (const float*)d_in[4];
  const float* w_proj = (const float*)d_in[5];
  const float* b_proj = (const float*)d_in[6];
  float* out = (float*)d_out;

  char* ws = (char*)d_ws;
  short* xn_t = (short*)(ws);                  // 8 MB   (B,N,C) bf16
  short* wqkv_b = (short*)(ws + 8388608);      // 1.5 MB
  short* wproj_b = (short*)(ws + 9961472);     // 0.5 MB
  short* qbuf = (short*)(ws + 10485760);       // 8 MB   (BH,N,d)
  short* kbuf = (short*)(ws + 18874368);       // 8 MB   (BH,N,d)
  short* vtbuf = (short*)(ws + 27262976);      // 8 MB   (BH,d,N)
  short* aobuf = (short*)(ws + 35651584);      // 8 MB   (B,N,C)

  gn_kernel<<<dim3(256), dim3(256), 0, stream>>>(x, gamma, beta, xn_t);
  f2bf_kernel<<<dim3(768), dim3(256), 0, stream>>>(w_qkv, wqkv_b, 196608);
  f2bf_kernel<<<dim3(256), dim3(256), 0, stream>>>(w_proj, wproj_b, 65536);
  qkv_gemm<<<dim3(8, 12, 8), dim3(256), 0, stream>>>(wqkv_b, xn_t, b_qkv, qbuf, kbuf,
                                                     vtbuf);
  attn_kernel<<<dim3(8, 8, 8), dim3(256), 0, stream>>>(qbuf, kbuf, vtbuf, aobuf);
  proj_gemm<<<dim3(8, 4, 8), dim3(256), 0, stream>>>(wproj_b, aobuf, b_proj, x, out);
}